// Round 1
// baseline (114.311 us; speedup 1.0000x reference)
//
#include <hip/hip_runtime.h>

// Problem constants (from reference setup_inputs):
//   B=4096 (objects), C=4096 (channels), M=64, S=64 -> M*S = 4096 slots.
// Semantics: out[b,c] = count[b] * x[b,c], where
//   count[b] = #{(m,s) : assignments[m,s] == b, assignments[m,s] >= 0}.

__global__ void mux_count_kernel(const int* __restrict__ assignments, int ms,
                                 int* __restrict__ count) {
    int i = blockIdx.x * blockDim.x + threadIdx.x;
    if (i < ms) {
        int a = assignments[i];
        if (a >= 0) atomicAdd(&count[a], 1);
    }
}

__global__ void mux_scale_kernel(const float4* __restrict__ x,
                                 const int* __restrict__ count,
                                 float4* __restrict__ out, int c_vec) {
    int b = blockIdx.y;
    int j = blockIdx.x * blockDim.x + threadIdx.x;
    if (j < c_vec) {
        float s = (float)count[b];
        long i = (long)b * c_vec + j;
        float4 v = x[i];
        v.x *= s; v.y *= s; v.z *= s; v.w *= s;
        out[i] = v;
    }
}

extern "C" void kernel_launch(void* const* d_in, const int* in_sizes, int n_in,
                              void* d_out, int out_size, void* d_ws, size_t ws_size,
                              hipStream_t stream) {
    const float* x = (const float*)d_in[0];
    const int* assignments = (const int*)d_in[1];
    float* out = (float*)d_out;

    const int B = 4096;
    const int C = 4096;
    const int ms = in_sizes[1];      // M*S = 4096
    const int c_vec = C / 4;         // 1024 float4 per row

    int* count = (int*)d_ws;         // B ints = 16 KB scratch

    // 1) zero counts (async memset is graph-capture safe)
    hipMemsetAsync(count, 0, (size_t)B * sizeof(int), stream);

    // 2) histogram of assignments
    {
        dim3 block(256);
        dim3 grid((ms + 255) / 256);
        mux_count_kernel<<<grid, block, 0, stream>>>(assignments, ms, count);
    }

    // 3) out[b,:] = count[b] * x[b,:]  (streaming, float4-vectorized)
    {
        dim3 block(256);
        dim3 grid((c_vec + 255) / 256, B);
        mux_scale_kernel<<<grid, block, 0, stream>>>((const float4*)x, count,
                                                     (float4*)out, c_vec);
    }
}

// Round 2
// 112.086 us; speedup vs baseline: 1.0199x; 1.0199x over previous
//
#include <hip/hip_runtime.h>

// Problem constants (from reference setup_inputs):
//   B=4096 (objects/rows), C=4096 (channels), M=64, S=64 -> M*S = 4096 slots.
// Algebraic collapse of the reference:
//   out[b,c] = count[b] * x[b,c], where
//   count[b] = #{(m,s) : assignments[m,s] == b}   (b >= 0, so -1 padding never matches)
//
// Single fused kernel: one block per row b. Each block
//   1) issues its 4 float4 x-loads (in flight during the count),
//   2) scans the 16 KB assignments array (L2-resident) counting matches to b,
//   3) shuffle+LDS reduces the count, broadcasts,
//   4) scales and stores the row.
// No memset, no atomics, no inter-kernel dependencies: one dispatch total.

#define BLOCK 256
#define C_VEC 1024            // 4096 floats / 4 per float4
#define VPT 4                 // float4 per thread (1024 / 256)
#define MS_VEC 1024           // 4096 assignment ints / 4 per int4
#define APT 4                 // int4 per thread (1024 / 256)

__global__ __launch_bounds__(BLOCK) void mux_fused_kernel(
    const float4* __restrict__ x,
    const int4* __restrict__ a4,
    float4* __restrict__ out) {
    const int b = blockIdx.x;
    const int tid = threadIdx.x;

    // 1) start the row loads early so they overlap the count/reduce
    const long base = (long)b * C_VEC;
    float4 v[VPT];
#pragma unroll
    for (int k = 0; k < VPT; ++k)
        v[k] = x[base + tid + BLOCK * k];

    // 2) per-thread match count over assignments (int4 loads, L2-hit)
    int local = 0;
#pragma unroll
    for (int k = 0; k < APT; ++k) {
        int4 a = a4[tid + BLOCK * k];
        local += (a.x == b) + (a.y == b) + (a.z == b) + (a.w == b);
    }

    // 3) wave shuffle-reduce (width 64) then cross-wave LDS reduce
#pragma unroll
    for (int off = 32; off > 0; off >>= 1)
        local += __shfl_down(local, off, 64);

    __shared__ int wave_sum[BLOCK / 64];
    __shared__ float s_scale;
    const int wave = tid >> 6;
    if ((tid & 63) == 0) wave_sum[wave] = local;
    __syncthreads();
    if (tid == 0)
        s_scale = (float)(wave_sum[0] + wave_sum[1] + wave_sum[2] + wave_sum[3]);
    __syncthreads();
    const float s = s_scale;

    // 4) scale + store
#pragma unroll
    for (int k = 0; k < VPT; ++k) {
        float4 w = v[k];
        w.x *= s; w.y *= s; w.z *= s; w.w *= s;
        out[base + tid + BLOCK * k] = w;
    }
}

extern "C" void kernel_launch(void* const* d_in, const int* in_sizes, int n_in,
                              void* d_out, int out_size, void* d_ws, size_t ws_size,
                              hipStream_t stream) {
    const float* x = (const float*)d_in[0];
    const int* assignments = (const int*)d_in[1];
    float* out = (float*)d_out;

    const int B = 4096;  // rows; one block each
    mux_fused_kernel<<<dim3(B), dim3(BLOCK), 0, stream>>>(
        (const float4*)x, (const int4*)assignments, (float4*)out);
}